// Round 8
// baseline (211.953 us; speedup 1.0000x reference)
//
#include <hip/hip_runtime.h>

#define B_ 16
#define N_ 4096
#define C_ 256
#define K_ 8
#define EPS 1e-6f
#define RATIO 0.1f

typedef float f32x4 __attribute__((ext_vector_type(4)));
typedef __bf16 bf16x8 __attribute__((ext_vector_type(8)));

__device__ inline unsigned short f2bf(float f){
  unsigned int u = __float_as_uint(f);
  u += 0x7FFFu + ((u >> 16) & 1u);   // RNE
  return (unsigned short)(u >> 16);
}
__device__ inline float bf2f(unsigned short h){
  return __uint_as_float(((unsigned int)h) << 16);
}

union BFu { ushort4 u4[2]; bf16x8 v; };

// ---------------- kA (R15=R14 fixed): gate + tok_bf emit + per-block records.
// ZERO global atomics. Absorbs k0: W1swz slice per block, Wg hi/lo frags in
// LDS, glog per block. Outputs: tok_bf, tokexp, lcnt_blk[1024][8],
// mass_blk[1024][8], conf_blk[1024]  (R14 BUG: conf_blk aliased a 64-byte
// buffer -> overran cnt/mass/bwi; now a dedicated 4 KB slot).
__global__ __launch_bounds__(256) void kA_gate(
    const float* __restrict__ tokens, const float* __restrict__ geno,
    const float* __restrict__ Wg, const float* __restrict__ bg,
    const float* __restrict__ Wgg, const float* __restrict__ bgg,
    const float* __restrict__ W1,
    unsigned short* __restrict__ W1swz, unsigned short* __restrict__ tok_bf,
    uint2* __restrict__ tokexp, int* __restrict__ lcnt_blk,
    float* __restrict__ mass_blk, float* __restrict__ conf_blk)
{
  __shared__ float ls[64][9];              // logits, +1 pad
  __shared__ unsigned short wgh[4096], wgl[4096];   // 16x256 (rows 8..15 zero)
  __shared__ float bg_s[K_], gl_s[K_], mass_s[K_];
  __shared__ int lcnt[K_];
  __shared__ float cred[4];
  int tid = threadIdx.x, lane = tid & 63, wave = tid >> 6;
  int quad = lane >> 4, l16 = lane & 15;
  int blk = blockIdx.x;
  int b = blk >> 6;
  int tok0 = (blk & 63) * 64;

  // --- k0-absorbed: W1swz slice (this block's 512 ushorts) ---
  if (tid < 64){
    int g = blk*64 + tid;                  // same decode as old k0, gid=g
    int o = g << 3;
    int lane6 = (o >> 3) & 63;
    int s  = (o >> 9) & 7;
    int nt = (o >> 12) & 15;
    int k  = o >> 16;
    int q2 = lane6 >> 4, r16 = lane6 & 15;
    const float* src = W1 + (k << 16) + ((nt*16 + r16) << 8) + s*32 + q2*8;
    unsigned short* dst = W1swz + o;
    #pragma unroll
    for (int e = 0; e < 8; ++e) dst[e] = f2bf(src[e]);
  }
  // --- Wg -> hi/lo bf16 frag table in LDS (rows 8..15 zero) ---
  {
    f32x4 wa = *(const f32x4*)(Wg + tid*8);
    f32x4 wb = *(const f32x4*)(Wg + tid*8 + 4);
    #pragma unroll
    for (int e = 0; e < 4; ++e){
      unsigned short h = f2bf(wa[e]);
      wgh[tid*8 + e] = h;  wgl[tid*8 + e] = f2bf(wa[e] - bf2f(h));
      unsigned short h2 = f2bf(wb[e]);
      wgh[tid*8 + 4 + e] = h2;  wgl[tid*8 + 4 + e] = f2bf(wb[e] - bf2f(h2));
      wgh[2048 + tid*8 + e] = 0;      wgl[2048 + tid*8 + e] = 0;
      wgh[2048 + tid*8 + 4 + e] = 0;  wgl[2048 + tid*8 + 4 + e] = 0;
    }
  }
  if (tid < K_){ bg_s[tid] = bg[tid]; mass_s[tid] = 0.f; lcnt[tid] = 0; }
  // --- glog: k = wave*2 + (lane>=32), 32 lanes per dot ---
  {
    int k = wave*2 + (lane >> 5);
    int hl = lane & 31;
    f32x4 a0 = *(const f32x4*)(geno + b*C_ + hl*8);
    f32x4 a1 = *(const f32x4*)(geno + b*C_ + hl*8 + 4);
    f32x4 w0v = *(const f32x4*)(Wgg + k*C_ + hl*8);
    f32x4 w1v = *(const f32x4*)(Wgg + k*C_ + hl*8 + 4);
    float p = a0[0]*w0v[0] + a0[1]*w0v[1] + a0[2]*w0v[2] + a0[3]*w0v[3]
            + a1[0]*w1v[0] + a1[1]*w1v[1] + a1[2]*w1v[2] + a1[3]*w1v[3];
    #pragma unroll
    for (int off = 16; off; off >>= 1) p += __shfl_xor(p, off);
    if (hl == 0) gl_s[k] = RATIO * (p + bgg[k]);
  }
  __syncthreads();

  // --- phase 1: logits via 3-term split-precision MFMA; emit bf16 tokens ---
  {
    int trow = tok0 + wave*16 + l16;
    const float* xsrc = tokens + ((size_t)b*N_ + trow)*C_ + quad*8;
    unsigned short* bdst = tok_bf + (((size_t)(b*N_ + trow)) << 8) + quad*8;
    f32x4 xa[8], xb[8];
    #pragma unroll
    for (int s = 0; s < 8; ++s){
      xa[s] = *(const f32x4*)(xsrc + s*32);
      xb[s] = *(const f32x4*)(xsrc + s*32 + 4);
    }
    asm volatile("" : "+v"(xa[0]), "+v"(xa[1]), "+v"(xa[2]), "+v"(xa[3]),
                      "+v"(xa[4]), "+v"(xa[5]), "+v"(xa[6]), "+v"(xa[7]));
    asm volatile("" : "+v"(xb[0]), "+v"(xb[1]), "+v"(xb[2]), "+v"(xb[3]),
                      "+v"(xb[4]), "+v"(xb[5]), "+v"(xb[6]), "+v"(xb[7]));
    f32x4 acc; acc.x = 0.f; acc.y = 0.f; acc.z = 0.f; acc.w = 0.f;
    #pragma unroll
    for (int s = 0; s < 8; ++s){
      BFu hi, lo;
      hi.u4[0].x = f2bf(xa[s][0]); hi.u4[0].y = f2bf(xa[s][1]);
      hi.u4[0].z = f2bf(xa[s][2]); hi.u4[0].w = f2bf(xa[s][3]);
      hi.u4[1].x = f2bf(xb[s][0]); hi.u4[1].y = f2bf(xb[s][1]);
      hi.u4[1].z = f2bf(xb[s][2]); hi.u4[1].w = f2bf(xb[s][3]);
      lo.u4[0].x = f2bf(xa[s][0] - bf2f(hi.u4[0].x));
      lo.u4[0].y = f2bf(xa[s][1] - bf2f(hi.u4[0].y));
      lo.u4[0].z = f2bf(xa[s][2] - bf2f(hi.u4[0].z));
      lo.u4[0].w = f2bf(xa[s][3] - bf2f(hi.u4[0].w));
      lo.u4[1].x = f2bf(xb[s][0] - bf2f(hi.u4[1].x));
      lo.u4[1].y = f2bf(xb[s][1] - bf2f(hi.u4[1].y));
      lo.u4[1].z = f2bf(xb[s][2] - bf2f(hi.u4[1].z));
      lo.u4[1].w = f2bf(xb[s][3] - bf2f(hi.u4[1].w));
      *(ushort4*)(bdst + s*32)     = hi.u4[0];
      *(ushort4*)(bdst + s*32 + 4) = hi.u4[1];
      bf16x8 bhi = *(const bf16x8*)(wgh + l16*C_ + s*32 + quad*8);
      bf16x8 blo = *(const bf16x8*)(wgl + l16*C_ + s*32 + quad*8);
      acc = __builtin_amdgcn_mfma_f32_16x16x32_bf16(hi.v, bhi, acc, 0, 0, 0);
      acc = __builtin_amdgcn_mfma_f32_16x16x32_bf16(lo.v, bhi, acc, 0, 0, 0);
      acc = __builtin_amdgcn_mfma_f32_16x16x32_bf16(hi.v, blo, acc, 0, 0, 0);
    }
    if (l16 < K_){
      #pragma unroll
      for (int rr = 0; rr < 4; ++rr){
        int tl = wave*16 + quad*4 + rr;     // D row = quad*4+reg
        ls[tl][l16] = acc[rr] + bg_s[l16] + gl_s[l16];
      }
    }
  }
  __syncthreads();

  // --- phase 2: top-2 + softmax + LOCAL ranks (LDS atomics only) ---
  if (quad == 0){
    int t = (wave << 4) | l16;
    float v0 = -1e30f, v1 = -1e30f; int i0 = 0, i1 = 0;
    #pragma unroll
    for (int kk = 0; kk < K_; ++kk){
      float l = ls[t][kk];
      if (l > v0){ v1 = v0; i1 = i0; v0 = l; i0 = kk; }
      else if (l > v1){ v1 = l; i1 = kk; }
    }
    float e  = expf(v1 - v0);
    float w0 = 1.f / (1.f + e), w1 = e / (1.f + e);
    w0 = fmaxf(w0, EPS); w1 = fmaxf(w1, EPS);
    float inv = 1.f / (w0 + w1);
    w0 *= inv; w1 *= inv;
    int p0 = atomicAdd(&lcnt[i0], 1);      // block-local rank (LDS, fast)
    int p1 = atomicAdd(&lcnt[i1], 1);
    atomicAdd(&mass_s[i0], w0);
    atomicAdd(&mass_s[i1], w1);
    tokexp[(size_t)b*N_ + tok0 + t] =
      make_uint2((unsigned)(i0 | (i1 << 4) | (p0 << 8) | (p1 << 16)),
                 __float_as_uint(w0));
    float ca = v0 - v1;
    #pragma unroll
    for (int off = 8; off; off >>= 1) ca += __shfl_down(ca, off);
    if (l16 == 0) cred[wave] = ca;
  }
  __syncthreads();
  if (tid < K_){
    lcnt_blk[blk*K_ + tid] = lcnt[tid];
    mass_blk[blk*K_ + tid] = mass_s[tid];
  }
  if (tid == 0) conf_blk[blk] = cred[0] + cred[1] + cred[2] + cred[3];
}

// ---------------- kP (R15): per-batch prefix + compaction scatter ------------
// 16 blocks (1/batch). Wave 0: exclusive prefix of lcnt_blk over the batch's
// 64 blocks per expert -> bp[64][8], totals -> cnt; mass/conf reductions.
// Then all 256 threads scatter {token, weight} pairs to bwi at exact slots.
// conf input (conf_blk) and output (conf_b) are now DISTINCT buffers.
__global__ __launch_bounds__(256) void kP_prefix(
    const int* __restrict__ lcnt_blk, const float* __restrict__ mass_blk,
    const float* __restrict__ conf_blk, const uint2* __restrict__ tokexp,
    int* __restrict__ cnt, float* __restrict__ mass,
    float* __restrict__ conf_b, uint2* __restrict__ bwi)
{
  __shared__ int bp[64][K_];
  __shared__ int tot[K_];
  int b = blockIdx.x, tid = threadIdx.x, lane = tid & 63, wave = tid >> 6;
  if (wave == 0){
    #pragma unroll
    for (int k = 0; k < K_; ++k){
      int v = lcnt_blk[(b*64 + lane)*K_ + k];
      int ps = v;
      #pragma unroll
      for (int off = 1; off < 64; off <<= 1){
        int t = __shfl_up(ps, off);
        if (lane >= off) ps += t;
      }
      bp[lane][k] = ps - v;
      if (lane == 63) tot[k] = ps;
      float mv = mass_blk[(b*64 + lane)*K_ + k];
      #pragma unroll
      for (int off = 32; off; off >>= 1) mv += __shfl_xor(mv, off);
      if (lane == 0) mass[b*K_ + k] = mv;
    }
    float cv = conf_blk[b*64 + lane];
    #pragma unroll
    for (int off = 32; off; off >>= 1) cv += __shfl_xor(cv, off);
    if (lane == 0) conf_b[b] = cv;
  }
  __syncthreads();
  if (tid < K_) cnt[b*K_ + tid] = tot[tid];
  #pragma unroll 1
  for (int it = 0; it < 16; ++it){
    int n = it*256 + tid;
    uint2 te = tokexp[(size_t)b*N_ + n];
    int e0 = te.x & 15, e1 = (te.x >> 4) & 15;
    int p0 = (te.x >> 8) & 255, p1 = (te.x >> 16) & 255;
    int j = n >> 6;
    float w0 = __uint_as_float(te.y);
    float w1 = 1.f - w0;
    bwi[(size_t)(b*K_ + e0)*N_ + bp[j][e0] + p0] = make_uint2((unsigned)n, te.y);
    bwi[(size_t)(b*K_ + e1)*N_ + bp[j][e1] + p1] =
      make_uint2((unsigned)n, __float_as_uint(w1));
  }
}

// ---------------- K4 (R15=R14): 3-region ring (24KB) -> 5 blocks/CU ----------
// LDS was the occupancy cap (33.5KB -> 4 blocks/CU, 16 waves). 3-region ring
// with stage-AFTER-barrier keeps WAR safety (stage(p+2) targets (p+2)%3 ==
// (p-1)%3, whose readers all passed barrier(p)); vmcnt(2) forces stage(p)
// complete (oldest-first FIFO). ~26KB -> 5 blocks/CU, launch_bounds(256,5).
#define K4_STAGE(T, REG) do {                                                  \
    _Pragma("unroll")                                                          \
    for (int i = 0; i < 2; ++i){                                               \
      int c16 = (T)*512 + i*256 + tid;                                         \
      __builtin_amdgcn_global_load_lds(                                        \
        (const __attribute__((address_space(1))) unsigned int*)(wsrc + c16*8), \
        (__attribute__((address_space(3))) unsigned int*)(&Bs[REG][0] + (i*256 + tid)*8), \
        16, 0, 0);                                                             \
    }                                                                          \
  } while(0)

__global__ __launch_bounds__(256, 5) void k4_expert(
    const unsigned short* __restrict__ tok_bf, const unsigned short* __restrict__ W1swz,
    const float* __restrict__ b1, const int* __restrict__ cnt,
    const uint2* __restrict__ bwi, float* __restrict__ gpart)
{
  __shared__ unsigned short Bs[3][4096];   // 24 KB: 3-region ring, 8 KB tiles
  __shared__ float wtok[128];
  __shared__ float red[2][4][16];
  __shared__ int Pb[129];

  int tid = threadIdx.x, lane = tid & 63, wave = tid >> 6;
  int quad = lane >> 4, l16 = lane & 15;

  if (wave == 0){                          // exclusive chunk-prefix, 2 buckets/lane
    int b2i = lane << 1;
    int cA = (cnt[b2i] + 127) >> 7;
    int cB = (cnt[b2i + 1] + 127) >> 7;
    int s = cA + cB;
    int ps = s;
    #pragma unroll
    for (int off = 1; off < 64; off <<= 1){
      int t = __shfl_up(ps, off);
      if (lane >= off) ps += t;
    }
    Pb[b2i]     = ps - s;
    Pb[b2i + 1] = ps - cB;
    if (lane == 63) Pb[128] = ps;
  }
  __syncthreads();

  int T = Pb[128];
  int lin = blockIdx.x;                    // 0..1151; XCD-contiguous work ranges
  int wq = (lin & 7) * 144 + (lin >> 3);
  if (wq >= T) return;                     // whole-block uniform exit
  int lo = 0, hi = 128;
  #pragma unroll
  for (int it = 0; it < 7; ++it){          // Pb[lo] <= wq < Pb[hi]
    int mid = (lo + hi) >> 1;
    if (Pb[mid] <= wq) lo = mid; else hi = mid;
  }
  int bucket = lo;
  int chunk = wq - Pb[lo];
  int bat = bucket >> 3, k = bucket & 7;
  int M = cnt[bucket];
  int Mm1 = M - 1;
  size_t bwbase = (size_t)bucket * N_;

  const unsigned short* wsrc = W1swz + ((size_t)k << 16);

  // prologue: stage tiles 0,1 (stage 2 is issued inside iter 0, post-barrier)
  K4_STAGE(0, 0);
  K4_STAGE(1, 1);

  if (tid < 128){
    int tn = chunk*128 + tid;
    uint2 e = bwi[bwbase + min(tn, Mm1)];
    wtok[tid] = (tn < M) ? __uint_as_float(e.y) : 0.f;
  }

  // gather A fragments once; reused across all 16 tiles
  int r0 = chunk*128 + (wave << 4) + l16;
  uint2 ev0 = bwi[bwbase + min(r0, Mm1)];
  uint2 ev1 = bwi[bwbase + min(r0 + 64, Mm1)];
  int nn0 = (int)ev0.x, nn1 = (int)ev1.x;
  const unsigned short* p0 = tok_bf + (((size_t)((bat << 12) + nn0)) << 8) + (quad << 3);
  const unsigned short* p1 = tok_bf + (((size_t)((bat << 12) + nn1)) << 8) + (quad << 3);
  bf16x8 a0[8], a1[8];
  #pragma unroll
  for (int s = 0; s < 8; ++s){
    a0[s] = *(const bf16x8*)(p0 + s*32);
    a1[s] = *(const bf16x8*)(p1 + s*32);
  }

  float bias[16];
  #pragma unroll
  for (int p = 0; p < 16; ++p) bias[p] = b1[(k << 8) + (p << 4) + l16];

  float* gdst = gpart + (size_t)(((bucket << 5) + chunk) << 8);
  int wq4 = (wave << 4) + (quad << 2);

  #pragma unroll
  for (int p = 0; p < 16; ++p){
    if (p < 15) asm volatile("s_waitcnt vmcnt(2) lgkmcnt(0)" ::: "memory");
    else        asm volatile("s_waitcnt vmcnt(0) lgkmcnt(0)" ::: "memory");
    __builtin_amdgcn_s_barrier();

    if (p > 0 && tid < 16){                // tile p-1 cross-wave sum + store
      int pb = (p - 1) & 1;
      float sv = red[pb][0][tid] + red[pb][1][tid]
               + red[pb][2][tid] + red[pb][3][tid];
      gdst[((p - 1) << 4) + tid] = sv;
    }
    if (p <= 13) K4_STAGE(p + 2, (p + 2) % 3);

    f32x4 acc0, acc1;
    acc0.x=0.f; acc0.y=0.f; acc0.z=0.f; acc0.w=0.f;
    acc1.x=0.f; acc1.y=0.f; acc1.z=0.f; acc1.w=0.f;
    #pragma unroll
    for (int s = 0; s < 8; ++s){
      bf16x8 bb = *(const bf16x8*)(&Bs[p % 3][0] + ((s*64 + lane) << 3));
      acc0 = __builtin_amdgcn_mfma_f32_16x16x32_bf16(a0[s], bb, acc0, 0, 0, 0);
      acc1 = __builtin_amdgcn_mfma_f32_16x16x32_bf16(a1[s], bb, acc1, 0, 0, 0);
    }
    float pt = 0.f;
    #pragma unroll
    for (int rr = 0; rr < 4; ++rr){
      float h0 = fmaxf(acc0[rr] + bias[p], 0.f);
      float h1 = fmaxf(acc1[rr] + bias[p], 0.f);
      pt += wtok[wq4 + rr] * h0 + wtok[64 + wq4 + rr] * h1;
    }
    pt += __shfl_down(pt, 32);
    pt += __shfl_down(pt, 16);
    if (lane < 16) red[p & 1][wave][lane] = pt;
  }
  asm volatile("s_waitcnt lgkmcnt(0)" ::: "memory");
  __builtin_amdgcn_s_barrier();
  if (tid < 16){                           // tail: tile 15
    float sv = red[1][0][tid] + red[1][1][tid] + red[1][2][tid] + red[1][3][tid];
    gdst[(15 << 4) + tid] = sv;
  }
}

// ---------------- K5: reduce chunk partials + layer-2 + divide by mass
//                  (+ fused scalars: lb_loss & routing confidence) -----------
__global__ __launch_bounds__(256) void k5_centers(
    const float* __restrict__ gpart, const int* __restrict__ cnt,
    const float* __restrict__ W2, const float* __restrict__ b2,
    const float* __restrict__ mass, const float* __restrict__ conf_b,
    float* __restrict__ out)
{
  __shared__ float gv[C_];
  int z = blockIdx.x, tid = threadIdx.x;
  int k = z & 7;
  int nch = (cnt[z] + 127) >> 7;
  float sv = 0.f;
  for (int c = 0; c < nch; ++c)
    sv += gpart[(size_t)((((z << 5) + c) << 8) + tid)];
  gv[tid] = sv;
  __syncthreads();
  float m = mass[z];
  float inv = 1.f / fmaxf(m, EPS);
  int tq = tid & 3, cb = tid >> 2;
  #pragma unroll 1
  for (int h = 0; h < 2; ++h){
    int c = (blockIdx.y*2 + h)*64 + cb;
    const float4* wrow = (const float4*)(W2 + ((((k << 8) + c)) << 8));
    float dot = 0.f;
    #pragma unroll
    for (int jj = 0; jj < 16; ++jj){
      float4 w4 = wrow[jj*4 + tq];
      float4 g4 = *(const float4*)&gv[(jj*4 + tq) * 4];
      dot += w4.x*g4.x + w4.y*g4.y + w4.z*g4.z + w4.w*g4.w;
    }
    dot += __shfl_xor(dot, 1);
    dot += __shfl_xor(dot, 2);
    if (tq == 0) out[z*C_ + c] = (dot + m * b2[k*C_ + c]) * inv;
  }
  if (z == 0 && blockIdx.y == 0 && tid == 0){   // fused k2 (single thread)
    float u[K_];
    #pragma unroll
    for (int kk = 0; kk < K_; ++kk) u[kk] = 0.f;
    for (int i = 0; i < B_*K_; ++i) u[i & 7] += (float)cnt[i];
    float mean = 0.f;
    #pragma unroll
    for (int kk = 0; kk < K_; ++kk){ u[kk] *= (1.f / (float)(B_*N_)); mean += u[kk]; }
    mean *= (1.f / K_);
    float var = 0.f;
    #pragma unroll
    for (int kk = 0; kk < K_; ++kk){ float d = u[kk] - mean; var += d*d; }
    var *= (1.f / K_);
    float denom = mean + EPS;
    float cs = 0.f;
    for (int i = 0; i < B_; ++i) cs += conf_b[i];
    out[B_*K_*C_]     = var / (denom * denom);
    out[B_*K_*C_ + 1] = cs / (float)(B_*N_);
  }
}

extern "C" void kernel_launch(void* const* d_in, const int* in_sizes, int n_in,
                              void* d_out, int out_size, void* d_ws, size_t ws_size,
                              hipStream_t stream)
{
  const float* tokens = (const float*)d_in[0];
  const float* geno   = (const float*)d_in[1];
  const float* Wg     = (const float*)d_in[2];
  const float* bg     = (const float*)d_in[3];
  const float* Wgg    = (const float*)d_in[4];
  const float* bgg    = (const float*)d_in[5];
  const float* W1     = (const float*)d_in[6];
  const float* b1     = (const float*)d_in[7];
  const float* W2     = (const float*)d_in[8];
  const float* b2     = (const float*)d_in[9];
  float* out = (float*)d_out;
  char* ws = (char*)d_ws;
  unsigned short* W1swz = (unsigned short*)(ws);               // 1,048,576
  uint2* tokexp   = (uint2*)(ws + 1048576);                    //   524,288
  int*   lcnt_blk = (int*)  (ws + 1572864);                    //    32,768
  float* mass_blk = (float*)(ws + 1605632);                    //    32,768
  float* conf_blk = (float*)(ws + 1638400);                    //     4,096  (R14 bug: was 64 B)
  float* conf_b   = (float*)(ws + 1642496);                    //        64
  int*   cnt      = (int*)  (ws + 1642560);                    //       512
  float* mass     = (float*)(ws + 1643072);                    //       512
  uint2* bwi      = (uint2*)(ws + 1643584);                    // 4,194,304
  unsigned short* tok_bf = (unsigned short*)(ws + 5837888);    // 33,554,432
  float* gpart    = (float*)(ws + 39392320);                   // 4,194,304

  kA_gate<<<1024, 256, 0, stream>>>(tokens, geno, Wg, bg, Wgg, bgg, W1,
                                    W1swz, tok_bf, tokexp, lcnt_blk,
                                    mass_blk, conf_blk);
  kP_prefix<<<16, 256, 0, stream>>>(lcnt_blk, mass_blk, conf_blk, tokexp,
                                    cnt, mass, conf_b, bwi);
  k4_expert<<<1152, 256, 0, stream>>>(tok_bf, W1swz, b1, cnt, bwi, gpart);
  k5_centers<<<dim3(128, 2), 256, 0, stream>>>(gpart, cnt, W2, b2, mass,
                                               conf_b, out);
}

// Round 9
// 181.353 us; speedup vs baseline: 1.1687x; 1.1687x over previous
//
#include <hip/hip_runtime.h>

#define B_ 16
#define N_ 4096
#define C_ 256
#define K_ 8
#define EPS 1e-6f
#define RATIO 0.1f

typedef float f32x4 __attribute__((ext_vector_type(4)));
typedef __bf16 bf16x8 __attribute__((ext_vector_type(8)));

__device__ inline unsigned short f2bf(float f){
  unsigned int u = __float_as_uint(f);
  u += 0x7FFFu + ((u >> 16) & 1u);   // RNE
  return (unsigned short)(u >> 16);
}
__device__ inline float bf2f(unsigned short h){
  return __uint_as_float(((unsigned int)h) << 16);
}

union BFu { ushort4 u4[2]; bf16x8 v; };

// ---------------- kA (R16=R15): gate + tok_bf emit + per-block records. ------
__global__ __launch_bounds__(256) void kA_gate(
    const float* __restrict__ tokens, const float* __restrict__ geno,
    const float* __restrict__ Wg, const float* __restrict__ bg,
    const float* __restrict__ Wgg, const float* __restrict__ bgg,
    const float* __restrict__ W1,
    unsigned short* __restrict__ W1swz, unsigned short* __restrict__ tok_bf,
    uint2* __restrict__ tokexp, int* __restrict__ lcnt_blk,
    float* __restrict__ mass_blk, float* __restrict__ conf_blk)
{
  __shared__ float ls[64][9];              // logits, +1 pad
  __shared__ unsigned short wgh[4096], wgl[4096];   // 16x256 (rows 8..15 zero)
  __shared__ float bg_s[K_], gl_s[K_], mass_s[K_];
  __shared__ int lcnt[K_];
  __shared__ float cred[4];
  int tid = threadIdx.x, lane = tid & 63, wave = tid >> 6;
  int quad = lane >> 4, l16 = lane & 15;
  int blk = blockIdx.x;
  int b = blk >> 6;
  int tok0 = (blk & 63) * 64;

  // --- k0-absorbed: W1swz slice (this block's 512 ushorts) ---
  if (tid < 64){
    int g = blk*64 + tid;
    int o = g << 3;
    int lane6 = (o >> 3) & 63;
    int s  = (o >> 9) & 7;
    int nt = (o >> 12) & 15;
    int k  = o >> 16;
    int q2 = lane6 >> 4, r16 = lane6 & 15;
    const float* src = W1 + (k << 16) + ((nt*16 + r16) << 8) + s*32 + q2*8;
    unsigned short* dst = W1swz + o;
    #pragma unroll
    for (int e = 0; e < 8; ++e) dst[e] = f2bf(src[e]);
  }
  // --- Wg -> hi/lo bf16 frag table in LDS (rows 8..15 zero) ---
  {
    f32x4 wa = *(const f32x4*)(Wg + tid*8);
    f32x4 wb = *(const f32x4*)(Wg + tid*8 + 4);
    #pragma unroll
    for (int e = 0; e < 4; ++e){
      unsigned short h = f2bf(wa[e]);
      wgh[tid*8 + e] = h;  wgl[tid*8 + e] = f2bf(wa[e] - bf2f(h));
      unsigned short h2 = f2bf(wb[e]);
      wgh[tid*8 + 4 + e] = h2;  wgl[tid*8 + 4 + e] = f2bf(wb[e] - bf2f(h2));
      wgh[2048 + tid*8 + e] = 0;      wgl[2048 + tid*8 + e] = 0;
      wgh[2048 + tid*8 + 4 + e] = 0;  wgl[2048 + tid*8 + 4 + e] = 0;
    }
  }
  if (tid < K_){ bg_s[tid] = bg[tid]; mass_s[tid] = 0.f; lcnt[tid] = 0; }
  // --- glog: k = wave*2 + (lane>=32), 32 lanes per dot ---
  {
    int k = wave*2 + (lane >> 5);
    int hl = lane & 31;
    f32x4 a0 = *(const f32x4*)(geno + b*C_ + hl*8);
    f32x4 a1 = *(const f32x4*)(geno + b*C_ + hl*8 + 4);
    f32x4 w0v = *(const f32x4*)(Wgg + k*C_ + hl*8);
    f32x4 w1v = *(const f32x4*)(Wgg + k*C_ + hl*8 + 4);
    float p = a0[0]*w0v[0] + a0[1]*w0v[1] + a0[2]*w0v[2] + a0[3]*w0v[3]
            + a1[0]*w1v[0] + a1[1]*w1v[1] + a1[2]*w1v[2] + a1[3]*w1v[3];
    #pragma unroll
    for (int off = 16; off; off >>= 1) p += __shfl_xor(p, off);
    if (hl == 0) gl_s[k] = RATIO * (p + bgg[k]);
  }
  __syncthreads();

  // --- phase 1: logits via 3-term split-precision MFMA; emit bf16 tokens ---
  {
    int trow = tok0 + wave*16 + l16;
    const float* xsrc = tokens + ((size_t)b*N_ + trow)*C_ + quad*8;
    unsigned short* bdst = tok_bf + (((size_t)(b*N_ + trow)) << 8) + quad*8;
    f32x4 xa[8], xb[8];
    #pragma unroll
    for (int s = 0; s < 8; ++s){
      xa[s] = *(const f32x4*)(xsrc + s*32);
      xb[s] = *(const f32x4*)(xsrc + s*32 + 4);
    }
    asm volatile("" : "+v"(xa[0]), "+v"(xa[1]), "+v"(xa[2]), "+v"(xa[3]),
                      "+v"(xa[4]), "+v"(xa[5]), "+v"(xa[6]), "+v"(xa[7]));
    asm volatile("" : "+v"(xb[0]), "+v"(xb[1]), "+v"(xb[2]), "+v"(xb[3]),
                      "+v"(xb[4]), "+v"(xb[5]), "+v"(xb[6]), "+v"(xb[7]));
    f32x4 acc; acc.x = 0.f; acc.y = 0.f; acc.z = 0.f; acc.w = 0.f;
    #pragma unroll
    for (int s = 0; s < 8; ++s){
      BFu hi, lo;
      hi.u4[0].x = f2bf(xa[s][0]); hi.u4[0].y = f2bf(xa[s][1]);
      hi.u4[0].z = f2bf(xa[s][2]); hi.u4[0].w = f2bf(xa[s][3]);
      hi.u4[1].x = f2bf(xb[s][0]); hi.u4[1].y = f2bf(xb[s][1]);
      hi.u4[1].z = f2bf(xb[s][2]); hi.u4[1].w = f2bf(xb[s][3]);
      lo.u4[0].x = f2bf(xa[s][0] - bf2f(hi.u4[0].x));
      lo.u4[0].y = f2bf(xa[s][1] - bf2f(hi.u4[0].y));
      lo.u4[0].z = f2bf(xa[s][2] - bf2f(hi.u4[0].z));
      lo.u4[0].w = f2bf(xa[s][3] - bf2f(hi.u4[0].w));
      lo.u4[1].x = f2bf(xb[s][0] - bf2f(hi.u4[1].x));
      lo.u4[1].y = f2bf(xb[s][1] - bf2f(hi.u4[1].y));
      lo.u4[1].z = f2bf(xb[s][2] - bf2f(hi.u4[1].z));
      lo.u4[1].w = f2bf(xb[s][3] - bf2f(hi.u4[1].w));
      *(ushort4*)(bdst + s*32)     = hi.u4[0];
      *(ushort4*)(bdst + s*32 + 4) = hi.u4[1];
      bf16x8 bhi = *(const bf16x8*)(wgh + l16*C_ + s*32 + quad*8);
      bf16x8 blo = *(const bf16x8*)(wgl + l16*C_ + s*32 + quad*8);
      acc = __builtin_amdgcn_mfma_f32_16x16x32_bf16(hi.v, bhi, acc, 0, 0, 0);
      acc = __builtin_amdgcn_mfma_f32_16x16x32_bf16(lo.v, bhi, acc, 0, 0, 0);
      acc = __builtin_amdgcn_mfma_f32_16x16x32_bf16(hi.v, blo, acc, 0, 0, 0);
    }
    if (l16 < K_){
      #pragma unroll
      for (int rr = 0; rr < 4; ++rr){
        int tl = wave*16 + quad*4 + rr;     // D row = quad*4+reg
        ls[tl][l16] = acc[rr] + bg_s[l16] + gl_s[l16];
      }
    }
  }
  __syncthreads();

  // --- phase 2: top-2 + softmax + LOCAL ranks (LDS atomics only) ---
  if (quad == 0){
    int t = (wave << 4) | l16;
    float v0 = -1e30f, v1 = -1e30f; int i0 = 0, i1 = 0;
    #pragma unroll
    for (int kk = 0; kk < K_; ++kk){
      float l = ls[t][kk];
      if (l > v0){ v1 = v0; i1 = i0; v0 = l; i0 = kk; }
      else if (l > v1){ v1 = l; i1 = kk; }
    }
    float e  = expf(v1 - v0);
    float w0 = 1.f / (1.f + e), w1 = e / (1.f + e);
    w0 = fmaxf(w0, EPS); w1 = fmaxf(w1, EPS);
    float inv = 1.f / (w0 + w1);
    w0 *= inv; w1 *= inv;
    int p0 = atomicAdd(&lcnt[i0], 1);      // block-local rank (LDS, fast)
    int p1 = atomicAdd(&lcnt[i1], 1);
    atomicAdd(&mass_s[i0], w0);
    atomicAdd(&mass_s[i1], w1);
    tokexp[(size_t)b*N_ + tok0 + t] =
      make_uint2((unsigned)(i0 | (i1 << 4) | (p0 << 8) | (p1 << 16)),
                 __float_as_uint(w0));
    float ca = v0 - v1;
    #pragma unroll
    for (int off = 8; off; off >>= 1) ca += __shfl_down(ca, off);
    if (l16 == 0) cred[wave] = ca;
  }
  __syncthreads();
  if (tid < K_){
    lcnt_blk[blk*K_ + tid] = lcnt[tid];
    mass_blk[blk*K_ + tid] = mass_s[tid];
  }
  if (tid == 0) conf_blk[blk] = cred[0] + cred[1] + cred[2] + cred[3];
}

// ---------------- kP (R16=R15): per-batch prefix + compaction scatter --------
__global__ __launch_bounds__(256) void kP_prefix(
    const int* __restrict__ lcnt_blk, const float* __restrict__ mass_blk,
    const float* __restrict__ conf_blk, const uint2* __restrict__ tokexp,
    int* __restrict__ cnt, float* __restrict__ mass,
    float* __restrict__ conf_b, uint2* __restrict__ bwi)
{
  __shared__ int bp[64][K_];
  __shared__ int tot[K_];
  int b = blockIdx.x, tid = threadIdx.x, lane = tid & 63, wave = tid >> 6;
  if (wave == 0){
    #pragma unroll
    for (int k = 0; k < K_; ++k){
      int v = lcnt_blk[(b*64 + lane)*K_ + k];
      int ps = v;
      #pragma unroll
      for (int off = 1; off < 64; off <<= 1){
        int t = __shfl_up(ps, off);
        if (lane >= off) ps += t;
      }
      bp[lane][k] = ps - v;
      if (lane == 63) tot[k] = ps;
      float mv = mass_blk[(b*64 + lane)*K_ + k];
      #pragma unroll
      for (int off = 32; off; off >>= 1) mv += __shfl_xor(mv, off);
      if (lane == 0) mass[b*K_ + k] = mv;
    }
    float cv = conf_blk[b*64 + lane];
    #pragma unroll
    for (int off = 32; off; off >>= 1) cv += __shfl_xor(cv, off);
    if (lane == 0) conf_b[b] = cv;
  }
  __syncthreads();
  if (tid < K_) cnt[b*K_ + tid] = tot[tid];
  #pragma unroll 1
  for (int it = 0; it < 16; ++it){
    int n = it*256 + tid;
    uint2 te = tokexp[(size_t)b*N_ + n];
    int e0 = te.x & 15, e1 = (te.x >> 4) & 15;
    int p0 = (te.x >> 8) & 255, p1 = (te.x >> 16) & 255;
    int j = n >> 6;
    float w0 = __uint_as_float(te.y);
    float w1 = 1.f - w0;
    bwi[(size_t)(b*K_ + e0)*N_ + bp[j][e0] + p0] = make_uint2((unsigned)n, te.y);
    bwi[(size_t)(b*K_ + e1)*N_ + bp[j][e1] + p1] =
      make_uint2((unsigned)n, __float_as_uint(w1));
  }
}

// ---------------- K4 (R16): R6-proven pipeline + batch-per-XCD mapping -------
// REVERT from R8's regression: 4-region ring (32 KB), stage-before-vmcnt(4)
// (depth-2), __launch_bounds__(256,4) -> VGPR cap 128 (R8's (256,5) forced
// VGPR=48 + ~44 MB scratch spill traffic: FETCH +40 MB, WRITE +48 MB).
// NEW: batch-per-XCD work map. XCD x owns batches x and x+8 (consecutive
// blockIdx round-robin XCDs; grid 1152 = 8 x 144 slots). Per-XCD L2 set while
// on one batch: 2 MB tok_bf slab + 1 MB W1swz + 0.25 MB bwi ~= 3.3 MB < 4 MB
// L2 (old map spanned 2.25 batches + all experts ~= 5-6 MB -> L3 latency).
// Per-batch chunks <= ceil(8192/128)+7 = 71; two batches <= 142 <= 144 slots.
#define K4_STAGE(T, REG) do {                                                  \
    _Pragma("unroll")                                                          \
    for (int i = 0; i < 2; ++i){                                               \
      int c16 = (T)*512 + i*256 + tid;                                         \
      __builtin_amdgcn_global_load_lds(                                        \
        (const __attribute__((address_space(1))) unsigned int*)(wsrc + c16*8), \
        (__attribute__((address_space(3))) unsigned int*)(&Bs[REG][0] + (i*256 + tid)*8), \
        16, 0, 0);                                                             \
    }                                                                          \
  } while(0)

__global__ __launch_bounds__(256, 4) void k4_expert(
    const unsigned short* __restrict__ tok_bf, const unsigned short* __restrict__ W1swz,
    const float* __restrict__ b1, const int* __restrict__ cnt,
    const uint2* __restrict__ bwi, float* __restrict__ gpart)
{
  __shared__ unsigned short Bs[4][4096];   // 32 KB: 4-region ring, 8 KB tiles
  __shared__ float wtok[128];
  __shared__ float red[2][4][16];
  __shared__ int Pb[129];

  int tid = threadIdx.x, lane = tid & 63, wave = tid >> 6;
  int quad = lane >> 4, l16 = lane & 15;

  if (wave == 0){                          // exclusive chunk-prefix, 2 buckets/lane
    int b2i = lane << 1;
    int cA = (cnt[b2i] + 127) >> 7;
    int cB = (cnt[b2i + 1] + 127) >> 7;
    int s = cA + cB;
    int ps = s;
    #pragma unroll
    for (int off = 1; off < 64; off <<= 1){
      int t = __shfl_up(ps, off);
      if (lane >= off) ps += t;
    }
    Pb[b2i]     = ps - s;
    Pb[b2i + 1] = ps - cB;
    if (lane == 63) Pb[128] = ps;
  }
  __syncthreads();

  // batch-per-XCD dense mapping: XCD x handles batches x, then x+8
  int xcd = blockIdx.x & 7, slot = blockIdx.x >> 3;   // slot 0..143
  int base0 = Pb[xcd << 3];
  int L1 = Pb[(xcd << 3) + 8] - base0;
  int wq;
  if (slot < L1){
    wq = base0 + slot;
  } else {
    int s2 = slot - L1;
    int base1 = Pb[(xcd + 8) << 3];
    int L2n = Pb[((xcd + 8) << 3) + 8] - base1;
    if (s2 >= L2n) return;                 // whole-block uniform exit
    wq = base1 + s2;
  }
  int lo = 0, hi = 128;
  #pragma unroll
  for (int it = 0; it < 7; ++it){          // Pb[lo] <= wq < Pb[hi]
    int mid = (lo + hi) >> 1;
    if (Pb[mid] <= wq) lo = mid; else hi = mid;
  }
  int bucket = lo;
  int chunk = wq - Pb[lo];
  int bat = bucket >> 3, k = bucket & 7;
  int M = cnt[bucket];
  int Mm1 = M - 1;
  size_t bwbase = (size_t)bucket * N_;

  const unsigned short* wsrc = W1swz + ((size_t)k << 16);

  // prologue: stage tiles 0,1
  K4_STAGE(0, 0);
  K4_STAGE(1, 1);

  if (tid < 128){
    int tn = chunk*128 + tid;
    uint2 e = bwi[bwbase + min(tn, Mm1)];
    wtok[tid] = (tn < M) ? __uint_as_float(e.y) : 0.f;
  }

  // gather A fragments once; reused across all 16 tiles
  int r0 = chunk*128 + (wave << 4) + l16;
  uint2 ev0 = bwi[bwbase + min(r0, Mm1)];
  uint2 ev1 = bwi[bwbase + min(r0 + 64, Mm1)];
  int nn0 = (int)ev0.x, nn1 = (int)ev1.x;
  const unsigned short* p0 = tok_bf + (((size_t)((bat << 12) + nn0)) << 8) + (quad << 3);
  const unsigned short* p1 = tok_bf + (((size_t)((bat << 12) + nn1)) << 8) + (quad << 3);
  bf16x8 a0[8], a1[8];
  #pragma unroll
  for (int s = 0; s < 8; ++s){
    a0[s] = *(const bf16x8*)(p0 + s*32);
    a1[s] = *(const bf16x8*)(p1 + s*32);
  }

  float bias[16];
  #pragma unroll
  for (int p = 0; p < 16; ++p) bias[p] = b1[(k << 8) + (p << 4) + l16];

  float* gdst = gpart + (size_t)(((bucket << 5) + chunk) << 8);
  int wq4 = (wave << 4) + (quad << 2);

  #pragma unroll
  for (int p = 0; p < 16; ++p){
    if (p < 14){
      K4_STAGE(p + 2, (p + 2) & 3);
      asm volatile("s_waitcnt vmcnt(4) lgkmcnt(0)" ::: "memory");
    } else if (p == 14){
      asm volatile("s_waitcnt vmcnt(2) lgkmcnt(0)" ::: "memory");
    } else {
      asm volatile("s_waitcnt vmcnt(0) lgkmcnt(0)" ::: "memory");
    }
    __builtin_amdgcn_s_barrier();

    if (p > 0 && tid < 16){                // tile p-1 cross-wave sum + store
      int pb = (p - 1) & 1;
      float sv = red[pb][0][tid] + red[pb][1][tid]
               + red[pb][2][tid] + red[pb][3][tid];
      gdst[((p - 1) << 4) + tid] = sv;
    }

    f32x4 acc0, acc1;
    acc0.x=0.f; acc0.y=0.f; acc0.z=0.f; acc0.w=0.f;
    acc1.x=0.f; acc1.y=0.f; acc1.z=0.f; acc1.w=0.f;
    #pragma unroll
    for (int s = 0; s < 8; ++s){
      bf16x8 bb = *(const bf16x8*)(&Bs[p & 3][0] + ((s*64 + lane) << 3));
      acc0 = __builtin_amdgcn_mfma_f32_16x16x32_bf16(a0[s], bb, acc0, 0, 0, 0);
      acc1 = __builtin_amdgcn_mfma_f32_16x16x32_bf16(a1[s], bb, acc1, 0, 0, 0);
    }
    float pt = 0.f;
    #pragma unroll
    for (int rr = 0; rr < 4; ++rr){
      float h0 = fmaxf(acc0[rr] + bias[p], 0.f);
      float h1 = fmaxf(acc1[rr] + bias[p], 0.f);
      pt += wtok[wq4 + rr] * h0 + wtok[64 + wq4 + rr] * h1;
    }
    pt += __shfl_down(pt, 32);
    pt += __shfl_down(pt, 16);
    if (lane < 16) red[p & 1][wave][lane] = pt;
  }
  asm volatile("s_waitcnt lgkmcnt(0)" ::: "memory");
  __builtin_amdgcn_s_barrier();
  if (tid < 16){                           // tail: tile 15
    float sv = red[1][0][tid] + red[1][1][tid] + red[1][2][tid] + red[1][3][tid];
    gdst[(15 << 4) + tid] = sv;
  }
}

// ---------------- K5: reduce chunk partials + layer-2 + divide by mass
//                  (+ fused scalars: lb_loss & routing confidence) -----------
__global__ __launch_bounds__(256) void k5_centers(
    const float* __restrict__ gpart, const int* __restrict__ cnt,
    const float* __restrict__ W2, const float* __restrict__ b2,
    const float* __restrict__ mass, const float* __restrict__ conf_b,
    float* __restrict__ out)
{
  __shared__ float gv[C_];
  int z = blockIdx.x, tid = threadIdx.x;
  int k = z & 7;
  int nch = (cnt[z] + 127) >> 7;
  float sv = 0.f;
  for (int c = 0; c < nch; ++c)
    sv += gpart[(size_t)((((z << 5) + c) << 8) + tid)];
  gv[tid] = sv;
  __syncthreads();
  float m = mass[z];
  float inv = 1.f / fmaxf(m, EPS);
  int tq = tid & 3, cb = tid >> 2;
  #pragma unroll 1
  for (int h = 0; h < 2; ++h){
    int c = (blockIdx.y*2 + h)*64 + cb;
    const float4* wrow = (const float4*)(W2 + ((((k << 8) + c)) << 8));
    float dot = 0.f;
    #pragma unroll
    for (int jj = 0; jj < 16; ++jj){
      float4 w4 = wrow[jj*4 + tq];
      float4 g4 = *(const float4*)&gv[(jj*4 + tq) * 4];
      dot += w4.x*g4.x + w4.y*g4.y + w4.z*g4.z + w4.w*g4.w;
    }
    dot += __shfl_xor(dot, 1);
    dot += __shfl_xor(dot, 2);
    if (tq == 0) out[z*C_ + c] = (dot + m * b2[k*C_ + c]) * inv;
  }
  if (z == 0 && blockIdx.y == 0 && tid == 0){   // fused k2 (single thread)
    float u[K_];
    #pragma unroll
    for (int kk = 0; kk < K_; ++kk) u[kk] = 0.f;
    for (int i = 0; i < B_*K_; ++i) u[i & 7] += (float)cnt[i];
    float mean = 0.f;
    #pragma unroll
    for (int kk = 0; kk < K_; ++kk){ u[kk] *= (1.f / (float)(B_*N_)); mean += u[kk]; }
    mean *= (1.f / K_);
    float var = 0.f;
    #pragma unroll
    for (int kk = 0; kk < K_; ++kk){ float d = u[kk] - mean; var += d*d; }
    var *= (1.f / K_);
    float denom = mean + EPS;
    float cs = 0.f;
    for (int i = 0; i < B_; ++i) cs += conf_b[i];
    out[B_*K_*C_]     = var / (denom * denom);
    out[B_*K_*C_ + 1] = cs / (float)(B_*N_);
  }
}

extern "C" void kernel_launch(void* const* d_in, const int* in_sizes, int n_in,
                              void* d_out, int out_size, void* d_ws, size_t ws_size,
                              hipStream_t stream)
{
  const float* tokens = (const float*)d_in[0];
  const float* geno   = (const float*)d_in[1];
  const float* Wg     = (const float*)d_in[2];
  const float* bg     = (const float*)d_in[3];
  const float* Wgg    = (const float*)d_in[4];
  const float* bgg    = (const float*)d_in[5];
  const float* W1     = (const float*)d_in[6];
  const float* b1     = (const float*)d_in[7];
  const float* W2     = (const float*)d_in[8];
  const float* b2     = (const float*)d_in[9];
  float* out = (float*)d_out;
  char* ws = (char*)d_ws;
  unsigned short* W1swz = (unsigned short*)(ws);               // 1,048,576
  uint2* tokexp   = (uint2*)(ws + 1048576);                    //   524,288
  int*   lcnt_blk = (int*)  (ws + 1572864);                    //    32,768
  float* mass_blk = (float*)(ws + 1605632);                    //    32,768
  float* conf_blk = (float*)(ws + 1638400);                    //     4,096
  float* conf_b   = (float*)(ws + 1642496);                    //        64
  int*   cnt      = (int*)  (ws + 1642560);                    //       512
  float* mass     = (float*)(ws + 1643072);                    //       512
  uint2* bwi      = (uint2*)(ws + 1643584);                    // 4,194,304
  unsigned short* tok_bf = (unsigned short*)(ws + 5837888);    // 33,554,432
  float* gpart    = (float*)(ws + 39392320);                   // 4,194,304

  kA_gate<<<1024, 256, 0, stream>>>(tokens, geno, Wg, bg, Wgg, bgg, W1,
                                    W1swz, tok_bf, tokexp, lcnt_blk,
                                    mass_blk, conf_blk);
  kP_prefix<<<16, 256, 0, stream>>>(lcnt_blk, mass_blk, conf_blk, tokexp,
                                    cnt, mass, conf_b, bwi);
  k4_expert<<<1152, 256, 0, stream>>>(tok_bf, W1swz, b1, cnt, bwi, gpart);
  k5_centers<<<dim3(128, 2), 256, 0, stream>>>(gpart, cnt, W2, b2, mass,
                                               conf_b, out);
}

// Round 10
// 177.659 us; speedup vs baseline: 1.1930x; 1.0208x over previous
//
#include <hip/hip_runtime.h>

#define B_ 16
#define N_ 4096
#define C_ 256
#define K_ 8
#define EPS 1e-6f
#define RATIO 0.1f

typedef float f32x4 __attribute__((ext_vector_type(4)));
typedef __bf16 bf16x8 __attribute__((ext_vector_type(8)));

__device__ inline unsigned short f2bf(float f){
  unsigned int u = __float_as_uint(f);
  u += 0x7FFFu + ((u >> 16) & 1u);   // RNE
  return (unsigned short)(u >> 16);
}
__device__ inline float bf2f(unsigned short h){
  return __uint_as_float(((unsigned int)h) << 16);
}

union BFu { ushort4 u4[2]; bf16x8 v; };

// tok_bf layout (R17, fragment-major): token n, col c = s*32 + q*8 + e lives at
//   (b*N + (n & ~15))*256 + s*512 + q*128 + (n&15)*8 + e.
// kA store for fixed (wave,s): addr = base + lane*8 shorts -> one 16 B store
// per lane, 1 KB contiguous per instruction (full 128 B lines; no
// write-allocate RMW). k4 reads the same 16 B cells at p + s*512.

// ---------------- kA (R17): gate + swizzled tok_bf emit + per-block records --
__global__ __launch_bounds__(256) void kA_gate(
    const float* __restrict__ tokens, const float* __restrict__ geno,
    const float* __restrict__ Wg, const float* __restrict__ bg,
    const float* __restrict__ Wgg, const float* __restrict__ bgg,
    const float* __restrict__ W1,
    unsigned short* __restrict__ W1swz, unsigned short* __restrict__ tok_bf,
    uint2* __restrict__ tokexp, int* __restrict__ lcnt_blk,
    float* __restrict__ mass_blk, float* __restrict__ conf_blk)
{
  __shared__ float ls[64][9];              // logits, +1 pad
  __shared__ unsigned short wgh[4096], wgl[4096];   // 16x256 (rows 8..15 zero)
  __shared__ float bg_s[K_], gl_s[K_], mass_s[K_];
  __shared__ int lcnt[K_];
  __shared__ float cred[4];
  int tid = threadIdx.x, lane = tid & 63, wave = tid >> 6;
  int quad = lane >> 4, l16 = lane & 15;
  int blk = blockIdx.x;
  int b = blk >> 6;
  int tok0 = (blk & 63) * 64;

  // --- k0-absorbed: W1swz slice (this block's 512 ushorts) ---
  if (tid < 64){
    int g = blk*64 + tid;
    int o = g << 3;
    int lane6 = (o >> 3) & 63;
    int s  = (o >> 9) & 7;
    int nt = (o >> 12) & 15;
    int k  = o >> 16;
    int q2 = lane6 >> 4, r16 = lane6 & 15;
    const float* src = W1 + (k << 16) + ((nt*16 + r16) << 8) + s*32 + q2*8;
    unsigned short* dst = W1swz + o;
    #pragma unroll
    for (int e = 0; e < 8; ++e) dst[e] = f2bf(src[e]);
  }
  // --- Wg -> hi/lo bf16 frag table in LDS (rows 8..15 zero) ---
  {
    f32x4 wa = *(const f32x4*)(Wg + tid*8);
    f32x4 wb = *(const f32x4*)(Wg + tid*8 + 4);
    #pragma unroll
    for (int e = 0; e < 4; ++e){
      unsigned short h = f2bf(wa[e]);
      wgh[tid*8 + e] = h;  wgl[tid*8 + e] = f2bf(wa[e] - bf2f(h));
      unsigned short h2 = f2bf(wb[e]);
      wgh[tid*8 + 4 + e] = h2;  wgl[tid*8 + 4 + e] = f2bf(wb[e] - bf2f(h2));
      wgh[2048 + tid*8 + e] = 0;      wgl[2048 + tid*8 + e] = 0;
      wgh[2048 + tid*8 + 4 + e] = 0;  wgl[2048 + tid*8 + 4 + e] = 0;
    }
  }
  if (tid < K_){ bg_s[tid] = bg[tid]; mass_s[tid] = 0.f; lcnt[tid] = 0; }
  // --- glog: k = wave*2 + (lane>=32), 32 lanes per dot ---
  {
    int k = wave*2 + (lane >> 5);
    int hl = lane & 31;
    f32x4 a0 = *(const f32x4*)(geno + b*C_ + hl*8);
    f32x4 a1 = *(const f32x4*)(geno + b*C_ + hl*8 + 4);
    f32x4 w0v = *(const f32x4*)(Wgg + k*C_ + hl*8);
    f32x4 w1v = *(const f32x4*)(Wgg + k*C_ + hl*8 + 4);
    float p = a0[0]*w0v[0] + a0[1]*w0v[1] + a0[2]*w0v[2] + a0[3]*w0v[3]
            + a1[0]*w1v[0] + a1[1]*w1v[1] + a1[2]*w1v[2] + a1[3]*w1v[3];
    #pragma unroll
    for (int off = 16; off; off >>= 1) p += __shfl_xor(p, off);
    if (hl == 0) gl_s[k] = RATIO * (p + bgg[k]);
  }
  __syncthreads();

  // --- phase 1: logits via 3-term split-precision MFMA; emit swizzled bf16 ---
  {
    int trow = tok0 + wave*16 + l16;
    const float* xsrc = tokens + ((size_t)b*N_ + trow)*C_ + quad*8;
    // fragment-major dst: one 16 B store per lane per s, lane-linear
    unsigned short* bdst = tok_bf + (((size_t)(b*N_ + tok0 + wave*16)) << 8)
                         + (quad << 7) + (l16 << 3);
    f32x4 xa[8], xb[8];
    #pragma unroll
    for (int s = 0; s < 8; ++s){
      xa[s] = *(const f32x4*)(xsrc + s*32);
      xb[s] = *(const f32x4*)(xsrc + s*32 + 4);
    }
    asm volatile("" : "+v"(xa[0]), "+v"(xa[1]), "+v"(xa[2]), "+v"(xa[3]),
                      "+v"(xa[4]), "+v"(xa[5]), "+v"(xa[6]), "+v"(xa[7]));
    asm volatile("" : "+v"(xb[0]), "+v"(xb[1]), "+v"(xb[2]), "+v"(xb[3]),
                      "+v"(xb[4]), "+v"(xb[5]), "+v"(xb[6]), "+v"(xb[7]));
    f32x4 acc; acc.x = 0.f; acc.y = 0.f; acc.z = 0.f; acc.w = 0.f;
    #pragma unroll
    for (int s = 0; s < 8; ++s){
      BFu hi, lo;
      hi.u4[0].x = f2bf(xa[s][0]); hi.u4[0].y = f2bf(xa[s][1]);
      hi.u4[0].z = f2bf(xa[s][2]); hi.u4[0].w = f2bf(xa[s][3]);
      hi.u4[1].x = f2bf(xb[s][0]); hi.u4[1].y = f2bf(xb[s][1]);
      hi.u4[1].z = f2bf(xb[s][2]); hi.u4[1].w = f2bf(xb[s][3]);
      lo.u4[0].x = f2bf(xa[s][0] - bf2f(hi.u4[0].x));
      lo.u4[0].y = f2bf(xa[s][1] - bf2f(hi.u4[0].y));
      lo.u4[0].z = f2bf(xa[s][2] - bf2f(hi.u4[0].z));
      lo.u4[0].w = f2bf(xa[s][3] - bf2f(hi.u4[0].w));
      lo.u4[1].x = f2bf(xb[s][0] - bf2f(hi.u4[1].x));
      lo.u4[1].y = f2bf(xb[s][1] - bf2f(hi.u4[1].y));
      lo.u4[1].z = f2bf(xb[s][2] - bf2f(hi.u4[1].z));
      lo.u4[1].w = f2bf(xb[s][3] - bf2f(hi.u4[1].w));
      *(bf16x8*)(bdst + (s << 9)) = hi.v;   // coalesced full-line store
      bf16x8 bhi = *(const bf16x8*)(wgh + l16*C_ + s*32 + quad*8);
      bf16x8 blo = *(const bf16x8*)(wgl + l16*C_ + s*32 + quad*8);
      acc = __builtin_amdgcn_mfma_f32_16x16x32_bf16(hi.v, bhi, acc, 0, 0, 0);
      acc = __builtin_amdgcn_mfma_f32_16x16x32_bf16(lo.v, bhi, acc, 0, 0, 0);
      acc = __builtin_amdgcn_mfma_f32_16x16x32_bf16(hi.v, blo, acc, 0, 0, 0);
    }
    if (l16 < K_){
      #pragma unroll
      for (int rr = 0; rr < 4; ++rr){
        int tl = wave*16 + quad*4 + rr;     // D row = quad*4+reg
        ls[tl][l16] = acc[rr] + bg_s[l16] + gl_s[l16];
      }
    }
  }
  __syncthreads();

  // --- phase 2: top-2 + softmax + LOCAL ranks (LDS atomics only) ---
  if (quad == 0){
    int t = (wave << 4) | l16;
    float v0 = -1e30f, v1 = -1e30f; int i0 = 0, i1 = 0;
    #pragma unroll
    for (int kk = 0; kk < K_; ++kk){
      float l = ls[t][kk];
      if (l > v0){ v1 = v0; i1 = i0; v0 = l; i0 = kk; }
      else if (l > v1){ v1 = l; i1 = kk; }
    }
    float e  = expf(v1 - v0);
    float w0 = 1.f / (1.f + e), w1 = e / (1.f + e);
    w0 = fmaxf(w0, EPS); w1 = fmaxf(w1, EPS);
    float inv = 1.f / (w0 + w1);
    w0 *= inv; w1 *= inv;
    int p0 = atomicAdd(&lcnt[i0], 1);      // block-local rank (LDS, fast)
    int p1 = atomicAdd(&lcnt[i1], 1);
    atomicAdd(&mass_s[i0], w0);
    atomicAdd(&mass_s[i1], w1);
    tokexp[(size_t)b*N_ + tok0 + t] =
      make_uint2((unsigned)(i0 | (i1 << 4) | (p0 << 8) | (p1 << 16)),
                 __float_as_uint(w0));
    float ca = v0 - v1;
    #pragma unroll
    for (int off = 8; off; off >>= 1) ca += __shfl_down(ca, off);
    if (l16 == 0) cred[wave] = ca;
  }
  __syncthreads();
  if (tid < K_){
    lcnt_blk[blk*K_ + tid] = lcnt[tid];
    mass_blk[blk*K_ + tid] = mass_s[tid];
  }
  if (tid == 0) conf_blk[blk] = cred[0] + cred[1] + cred[2] + cred[3];
}

// ---------------- kP (R17=R15): per-batch prefix + compaction scatter --------
__global__ __launch_bounds__(256) void kP_prefix(
    const int* __restrict__ lcnt_blk, const float* __restrict__ mass_blk,
    const float* __restrict__ conf_blk, const uint2* __restrict__ tokexp,
    int* __restrict__ cnt, float* __restrict__ mass,
    float* __restrict__ conf_b, uint2* __restrict__ bwi)
{
  __shared__ int bp[64][K_];
  __shared__ int tot[K_];
  int b = blockIdx.x, tid = threadIdx.x, lane = tid & 63, wave = tid >> 6;
  if (wave == 0){
    #pragma unroll
    for (int k = 0; k < K_; ++k){
      int v = lcnt_blk[(b*64 + lane)*K_ + k];
      int ps = v;
      #pragma unroll
      for (int off = 1; off < 64; off <<= 1){
        int t = __shfl_up(ps, off);
        if (lane >= off) ps += t;
      }
      bp[lane][k] = ps - v;
      if (lane == 63) tot[k] = ps;
      float mv = mass_blk[(b*64 + lane)*K_ + k];
      #pragma unroll
      for (int off = 32; off; off >>= 1) mv += __shfl_xor(mv, off);
      if (lane == 0) mass[b*K_ + k] = mv;
    }
    float cv = conf_blk[b*64 + lane];
    #pragma unroll
    for (int off = 32; off; off >>= 1) cv += __shfl_xor(cv, off);
    if (lane == 0) conf_b[b] = cv;
  }
  __syncthreads();
  if (tid < K_) cnt[b*K_ + tid] = tot[tid];
  #pragma unroll 1
  for (int it = 0; it < 16; ++it){
    int n = it*256 + tid;
    uint2 te = tokexp[(size_t)b*N_ + n];
    int e0 = te.x & 15, e1 = (te.x >> 4) & 15;
    int p0 = (te.x >> 8) & 255, p1 = (te.x >> 16) & 255;
    int j = n >> 6;
    float w0 = __uint_as_float(te.y);
    float w1 = 1.f - w0;
    bwi[(size_t)(b*K_ + e0)*N_ + bp[j][e0] + p0] = make_uint2((unsigned)n, te.y);
    bwi[(size_t)(b*K_ + e1)*N_ + bp[j][e1] + p1] =
      make_uint2((unsigned)n, __float_as_uint(w1));
  }
}

// ---------------- K4 (R17): R6-proven pipeline, swizzled tok_bf gather -------
#define K4_STAGE(T, REG) do {                                                  \
    _Pragma("unroll")                                                          \
    for (int i = 0; i < 2; ++i){                                               \
      int c16 = (T)*512 + i*256 + tid;                                         \
      __builtin_amdgcn_global_load_lds(                                        \
        (const __attribute__((address_space(1))) unsigned int*)(wsrc + c16*8), \
        (__attribute__((address_space(3))) unsigned int*)(&Bs[REG][0] + (i*256 + tid)*8), \
        16, 0, 0);                                                             \
    }                                                                          \
  } while(0)

__global__ __launch_bounds__(256, 4) void k4_expert(
    const unsigned short* __restrict__ tok_bf, const unsigned short* __restrict__ W1swz,
    const float* __restrict__ b1, const int* __restrict__ cnt,
    const uint2* __restrict__ bwi, float* __restrict__ gpart)
{
  __shared__ unsigned short Bs[4][4096];   // 32 KB: 4-region ring, 8 KB tiles
  __shared__ float wtok[128];
  __shared__ float red[2][4][16];
  __shared__ int Pb[129];

  int tid = threadIdx.x, lane = tid & 63, wave = tid >> 6;
  int quad = lane >> 4, l16 = lane & 15;

  if (wave == 0){                          // exclusive chunk-prefix, 2 buckets/lane
    int b2i = lane << 1;
    int cA = (cnt[b2i] + 127) >> 7;
    int cB = (cnt[b2i + 1] + 127) >> 7;
    int s = cA + cB;
    int ps = s;
    #pragma unroll
    for (int off = 1; off < 64; off <<= 1){
      int t = __shfl_up(ps, off);
      if (lane >= off) ps += t;
    }
    Pb[b2i]     = ps - s;
    Pb[b2i + 1] = ps - cB;
    if (lane == 63) Pb[128] = ps;
  }
  __syncthreads();

  // batch-per-XCD dense mapping: XCD x handles batches x, then x+8
  int xcd = blockIdx.x & 7, slot = blockIdx.x >> 3;   // slot 0..143
  int base0 = Pb[xcd << 3];
  int L1 = Pb[(xcd << 3) + 8] - base0;
  int wq;
  if (slot < L1){
    wq = base0 + slot;
  } else {
    int s2 = slot - L1;
    int base1 = Pb[(xcd + 8) << 3];
    int L2n = Pb[((xcd + 8) << 3) + 8] - base1;
    if (s2 >= L2n) return;                 // whole-block uniform exit
    wq = base1 + s2;
  }
  int lo = 0, hi = 128;
  #pragma unroll
  for (int it = 0; it < 7; ++it){          // Pb[lo] <= wq < Pb[hi]
    int mid = (lo + hi) >> 1;
    if (Pb[mid] <= wq) lo = mid; else hi = mid;
  }
  int bucket = lo;
  int chunk = wq - Pb[lo];
  int bat = bucket >> 3, k = bucket & 7;
  int M = cnt[bucket];
  int Mm1 = M - 1;
  size_t bwbase = (size_t)bucket * N_;

  const unsigned short* wsrc = W1swz + ((size_t)k << 16);

  // prologue: stage tiles 0,1
  K4_STAGE(0, 0);
  K4_STAGE(1, 1);

  if (tid < 128){
    int tn = chunk*128 + tid;
    uint2 e = bwi[bwbase + min(tn, Mm1)];
    wtok[tid] = (tn < M) ? __uint_as_float(e.y) : 0.f;
  }

  // gather A fragments once (fragment-major tok_bf); reused across all 16 tiles
  int r0 = chunk*128 + (wave << 4) + l16;
  uint2 ev0 = bwi[bwbase + min(r0, Mm1)];
  uint2 ev1 = bwi[bwbase + min(r0 + 64, Mm1)];
  int nn0 = (int)ev0.x, nn1 = (int)ev1.x;
  const unsigned short* p0 = tok_bf
      + (((size_t)((bat << 12) + (nn0 & ~15))) << 8) + (quad << 7) + ((nn0 & 15) << 3);
  const unsigned short* p1 = tok_bf
      + (((size_t)((bat << 12) + (nn1 & ~15))) << 8) + (quad << 7) + ((nn1 & 15) << 3);
  bf16x8 a0[8], a1[8];
  #pragma unroll
  for (int s = 0; s < 8; ++s){
    a0[s] = *(const bf16x8*)(p0 + (s << 9));
    a1[s] = *(const bf16x8*)(p1 + (s << 9));
  }

  float bias[16];
  #pragma unroll
  for (int p = 0; p < 16; ++p) bias[p] = b1[(k << 8) + (p << 4) + l16];

  float* gdst = gpart + (size_t)(((bucket << 5) + chunk) << 8);
  int wq4 = (wave << 4) + (quad << 2);

  #pragma unroll
  for (int p = 0; p < 16; ++p){
    if (p < 14){
      K4_STAGE(p + 2, (p + 2) & 3);
      asm volatile("s_waitcnt vmcnt(4) lgkmcnt(0)" ::: "memory");
    } else if (p == 14){
      asm volatile("s_waitcnt vmcnt(2) lgkmcnt(0)" ::: "memory");
    } else {
      asm volatile("s_waitcnt vmcnt(0) lgkmcnt(0)" ::: "memory");
    }
    __builtin_amdgcn_s_barrier();

    if (p > 0 && tid < 16){                // tile p-1 cross-wave sum + store
      int pb = (p - 1) & 1;
      float sv = red[pb][0][tid] + red[pb][1][tid]
               + red[pb][2][tid] + red[pb][3][tid];
      gdst[((p - 1) << 4) + tid] = sv;
    }

    f32x4 acc0, acc1;
    acc0.x=0.f; acc0.y=0.f; acc0.z=0.f; acc0.w=0.f;
    acc1.x=0.f; acc1.y=0.f; acc1.z=0.f; acc1.w=0.f;
    #pragma unroll
    for (int s = 0; s < 8; ++s){
      bf16x8 bb = *(const bf16x8*)(&Bs[p & 3][0] + ((s*64 + lane) << 3));
      acc0 = __builtin_amdgcn_mfma_f32_16x16x32_bf16(a0[s], bb, acc0, 0, 0, 0);
      acc1 = __builtin_amdgcn_mfma_f32_16x16x32_bf16(a1[s], bb, acc1, 0, 0, 0);
    }
    float pt = 0.f;
    #pragma unroll
    for (int rr = 0; rr < 4; ++rr){
      float h0 = fmaxf(acc0[rr] + bias[p], 0.f);
      float h1 = fmaxf(acc1[rr] + bias[p], 0.f);
      pt += wtok[wq4 + rr] * h0 + wtok[64 + wq4 + rr] * h1;
    }
    pt += __shfl_down(pt, 32);
    pt += __shfl_down(pt, 16);
    if (lane < 16) red[p & 1][wave][lane] = pt;
  }
  asm volatile("s_waitcnt lgkmcnt(0)" ::: "memory");
  __builtin_amdgcn_s_barrier();
  if (tid < 16){                           // tail: tile 15
    float sv = red[1][0][tid] + red[1][1][tid] + red[1][2][tid] + red[1][3][tid];
    gdst[(15 << 4) + tid] = sv;
  }
}

// ---------------- K5: reduce chunk partials + layer-2 + divide by mass
//                  (+ fused scalars: lb_loss & routing confidence) -----------
__global__ __launch_bounds__(256) void k5_centers(
    const float* __restrict__ gpart, const int* __restrict__ cnt,
    const float* __restrict__ W2, const float* __restrict__ b2,
    const float* __restrict__ mass, const float* __restrict__ conf_b,
    float* __restrict__ out)
{
  __shared__ float gv[C_];
  int z = blockIdx.x, tid = threadIdx.x;
  int k = z & 7;
  int nch = (cnt[z] + 127) >> 7;
  float sv = 0.f;
  for (int c = 0; c < nch; ++c)
    sv += gpart[(size_t)((((z << 5) + c) << 8) + tid)];
  gv[tid] = sv;
  __syncthreads();
  float m = mass[z];
  float inv = 1.f / fmaxf(m, EPS);
  int tq = tid & 3, cb = tid >> 2;
  #pragma unroll 1
  for (int h = 0; h < 2; ++h){
    int c = (blockIdx.y*2 + h)*64 + cb;
    const float4* wrow = (const float4*)(W2 + ((((k << 8) + c)) << 8));
    float dot = 0.f;
    #pragma unroll
    for (int jj = 0; jj < 16; ++jj){
      float4 w4 = wrow[jj*4 + tq];
      float4 g4 = *(const float4*)&gv[(jj*4 + tq) * 4];
      dot += w4.x*g4.x + w4.y*g4.y + w4.z*g4.z + w4.w*g4.w;
    }
    dot += __shfl_xor(dot, 1);
    dot += __shfl_xor(dot, 2);
    if (tq == 0) out[z*C_ + c] = (dot + m * b2[k*C_ + c]) * inv;
  }
  if (z == 0 && blockIdx.y == 0 && tid == 0){   // fused k2 (single thread)
    float u[K_];
    #pragma unroll
    for (int kk = 0; kk < K_; ++kk) u[kk] = 0.f;
    for (int i = 0; i < B_*K_; ++i) u[i & 7] += (float)cnt[i];
    float mean = 0.f;
    #pragma unroll
    for (int kk = 0; kk < K_; ++kk){ u[kk] *= (1.f / (float)(B_*N_)); mean += u[kk]; }
    mean *= (1.f / K_);
    float var = 0.f;
    #pragma unroll
    for (int kk = 0; kk < K_; ++kk){ float d = u[kk] - mean; var += d*d; }
    var *= (1.f / K_);
    float denom = mean + EPS;
    float cs = 0.f;
    for (int i = 0; i < B_; ++i) cs += conf_b[i];
    out[B_*K_*C_]     = var / (denom * denom);
    out[B_*K_*C_ + 1] = cs / (float)(B_*N_);
  }
}

extern "C" void kernel_launch(void* const* d_in, const int* in_sizes, int n_in,
                              void* d_out, int out_size, void* d_ws, size_t ws_size,
                              hipStream_t stream)
{
  const float* tokens = (const float*)d_in[0];
  const float* geno   = (const float*)d_in[1];
  const float* Wg     = (const float*)d_in[2];
  const float* bg     = (const float*)d_in[3];
  const float* Wgg    = (const float*)d_in[4];
  const float* bgg    = (const float*)d_in[5];
  const float* W1     = (const float*)d_in[6];
  const float* b1     = (const float*)d_in[7];
  const float* W2     = (const float*)d_in[8];
  const float* b2     = (const float*)d_in[9];
  float* out = (float*)d_out;
  char* ws = (char*)d_ws;
  unsigned short* W1swz = (unsigned short*)(ws);               // 1,048,576
  uint2* tokexp   = (uint2*)(ws + 1048576);                    //   524,288
  int*   lcnt_blk = (int*)  (ws + 1572864);                    //    32,768
  float* mass_blk = (float*)(ws + 1605632);                    //    32,768
  float* conf_blk = (float*)(ws + 1638400);                    //     4,096
  float* conf_b   = (float*)(ws + 1642496);                    //        64
  int*   cnt      = (int*)  (ws + 1642560);                    //       512
  float* mass     = (float*)(ws + 1643072);                    //       512
  uint2* bwi      = (uint2*)(ws + 1643584);                    // 4,194,304
  unsigned short* tok_bf = (unsigned short*)(ws + 5837888);    // 33,554,432
  float* gpart    = (float*)(ws + 39392320);                   // 4,194,304

  kA_gate<<<1024, 256, 0, stream>>>(tokens, geno, Wg, bg, Wgg, bgg, W1,
                                    W1swz, tok_bf, tokexp, lcnt_blk,
                                    mass_blk, conf_blk);
  kP_prefix<<<16, 256, 0, stream>>>(lcnt_blk, mass_blk, conf_blk, tokexp,
                                    cnt, mass, conf_b, bwi);
  k4_expert<<<1152, 256, 0, stream>>>(tok_bf, W1swz, b1, cnt, bwi, gpart);
  k5_centers<<<dim3(128, 2), 256, 0, stream>>>(gpart, cnt, W2, b2, mass,
                                               conf_b, out);
}